// Round 1
// baseline (320.829 us; speedup 1.0000x reference)
//
#include <hip/hip_runtime.h>
#include <cstddef>

#define NUM_BLOCKS 8
#define BLK 512
#define D_IN 2048
#define NROWS 8192
#define NBUCKETS (NUM_BLOCKS * BLK) /* 4096 */
#define CAP 32
#define ROWS_PER_WG 4
#define THREADS 256

// Build inverted index: for each bucket (b,k), the list of input dims d with
// i_hash[b,d]==k, packed as (d<<1)|signbit, stored TRANSPOSED
// (entries_t[e*NBUCKETS + bucket]) so the gather kernel's loads coalesce.
// Deterministic: entries appended in ascending d order.
__global__ __launch_bounds__(256) void cs_build_index(
    const int* __restrict__ i_hash, const float* __restrict__ s_hash,
    int* __restrict__ counts, int* __restrict__ entries_t)
{
    int t = blockIdx.x * blockDim.x + threadIdx.x; // bucket id in [0, 4096)
    if (t >= NBUCKETS) return;
    int b = t >> 9;          // which of the 8 blocks
    int k = t & (BLK - 1);   // bucket within block
    const int*   ih_row = i_hash + b * D_IN;
    const float* s_row  = s_hash + b * D_IN;
    int cnt = 0;
    for (int d = 0; d < D_IN; ++d) {
        // wave-uniform address (all lanes share b) -> broadcast load
        if (ih_row[d] == k) {
            if (cnt < CAP) {
                int sgnbit = (s_row[d] < 0.0f) ? 1 : 0;
                entries_t[cnt * NBUCKETS + t] = (d << 1) | sgnbit;
            }
            ++cnt;
        }
    }
    counts[t] = (cnt < CAP) ? cnt : CAP;
}

// Gather kernel: each WG stages ROWS_PER_WG rows of x in LDS, then each
// thread produces 16 output buckets for all 4 rows. All global loads and
// stores are coalesced; x is read from LDS at random (hash) positions.
__global__ __launch_bounds__(THREADS) void cs_gather(
    const float* __restrict__ x, const int* __restrict__ counts,
    const int* __restrict__ entries_t, float* __restrict__ out)
{
    __shared__ float xs[ROWS_PER_WG][D_IN]; // 32 KiB
    const int tid = threadIdx.x;
    const int n0  = blockIdx.x * ROWS_PER_WG;

    // Stage 4 rows (8 float4 loads per thread, fully coalesced)
    const float4* __restrict__ xv = (const float4*)(x + (size_t)n0 * D_IN);
    float4* sv = (float4*)&xs[0][0];
#pragma unroll
    for (int i = 0; i < (ROWS_PER_WG * D_IN / 4) / THREADS; ++i)
        sv[i * THREADS + tid] = xv[i * THREADS + tid];
    __syncthreads();

    const float scale = 0.35355339059327373f; // 1/sqrt(8)
#pragma unroll 1
    for (int jj = 0; jj < NBUCKETS / THREADS; ++jj) {
        const int j = jj * THREADS + tid;   // bucket / output column
        const int cnt = counts[j];          // coalesced
        float a0 = 0.f, a1 = 0.f, a2 = 0.f, a3 = 0.f;
        for (int e = 0; e < cnt; ++e) {
            int ent = entries_t[e * NBUCKETS + j]; // coalesced across lanes
            int d = ent >> 1;
            unsigned sg = ((unsigned)ent & 1u) << 31;
            a0 += __uint_as_float(__float_as_uint(xs[0][d]) ^ sg);
            a1 += __uint_as_float(__float_as_uint(xs[1][d]) ^ sg);
            a2 += __uint_as_float(__float_as_uint(xs[2][d]) ^ sg);
            a3 += __uint_as_float(__float_as_uint(xs[3][d]) ^ sg);
        }
        size_t o = (size_t)n0 * NBUCKETS + j; // coalesced stores
        out[o]                = a0 * scale;
        out[o + NBUCKETS]     = a1 * scale;
        out[o + 2 * NBUCKETS] = a2 * scale;
        out[o + 3 * NBUCKETS] = a3 * scale;
    }
}

extern "C" void kernel_launch(void* const* d_in, const int* in_sizes, int n_in,
                              void* d_out, int out_size, void* d_ws, size_t ws_size,
                              hipStream_t stream)
{
    const float* x      = (const float*)d_in[0];
    const float* s_hash = (const float*)d_in[1];
    const int*   i_hash = (const int*)d_in[2];
    float* out = (float*)d_out;

    // ws layout: counts[4096] ints, then entries_t[CAP*4096] ints (~528 KiB)
    int* counts    = (int*)d_ws;
    int* entries_t = counts + NBUCKETS;

    cs_build_index<<<NBUCKETS / 256, 256, 0, stream>>>(i_hash, s_hash, counts, entries_t);
    cs_gather<<<NROWS / ROWS_PER_WG, THREADS, 0, stream>>>(x, counts, entries_t, out);
}

// Round 2
// 94.467 us; speedup vs baseline: 3.3962x; 3.3962x over previous
//
#include <hip/hip_runtime.h>
#include <cstddef>

#define NUM_BLOCKS 8
#define BLK 512
#define D_IN 2048
#define NROWS 8192
#define NBUCKETS (NUM_BLOCKS * BLK) /* 4096 */
#define CAP 32
#define ROWS_PER_WG 4
#define THREADS 256

// Build inverted index: one WAVE per bucket. Lanes scan 64 dims per step,
// ballot-match, and place matches in ascending-d order via popcount prefix.
// Deterministic: slot order is ascending d regardless of scheduling.
__global__ __launch_bounds__(256) void cs_build_index(
    const int* __restrict__ i_hash, const float* __restrict__ s_hash,
    int* __restrict__ counts, int* __restrict__ entries_t)
{
    const int gid  = blockIdx.x * blockDim.x + threadIdx.x;
    const int wave = gid >> 6;            // bucket id in [0, 4096)
    const int lane = threadIdx.x & 63;
    if (wave >= NBUCKETS) return;
    const int b = wave >> 9;              // which of the 8 blocks
    const int k = wave & (BLK - 1);       // bucket within block
    const int*   ih = i_hash + b * D_IN;
    const float* sr = s_hash + b * D_IN;
    int cnt = 0;
    for (int d0 = 0; d0 < D_IN; d0 += 64) {
        const int d = d0 + lane;
        const bool m = (ih[d] == k);      // coalesced load
        const unsigned long long mask = __ballot(m);
        if (m) {
            const int pos = cnt + __popcll(mask & ((1ull << lane) - 1ull));
            if (pos < CAP) {
                const int sg = (sr[d] < 0.0f) ? 1 : 0;
                entries_t[pos * NBUCKETS + wave] = (d << 1) | sg;
            }
        }
        cnt += (int)__popcll(mask);
    }
    counts[wave] = (cnt < CAP) ? cnt : CAP;
}

// Gather kernel: each WG stages ROWS_PER_WG rows of x in LDS, then each
// thread produces 16 output buckets for all 4 rows. All global loads and
// stores are coalesced; x is read from LDS at random (hash) positions.
__global__ __launch_bounds__(THREADS) void cs_gather(
    const float* __restrict__ x, const int* __restrict__ counts,
    const int* __restrict__ entries_t, float* __restrict__ out)
{
    __shared__ float xs[ROWS_PER_WG][D_IN]; // 32 KiB
    const int tid = threadIdx.x;
    const int n0  = blockIdx.x * ROWS_PER_WG;

    // Stage 4 rows (8 float4 loads per thread, fully coalesced)
    const float4* __restrict__ xv = (const float4*)(x + (size_t)n0 * D_IN);
    float4* sv = (float4*)&xs[0][0];
#pragma unroll
    for (int i = 0; i < (ROWS_PER_WG * D_IN / 4) / THREADS; ++i)
        sv[i * THREADS + tid] = xv[i * THREADS + tid];
    __syncthreads();

    const float scale = 0.35355339059327373f; // 1/sqrt(8)
#pragma unroll 1
    for (int jj = 0; jj < NBUCKETS / THREADS; ++jj) {
        const int j = jj * THREADS + tid;   // bucket / output column
        const int cnt = counts[j];          // coalesced
        float a0 = 0.f, a1 = 0.f, a2 = 0.f, a3 = 0.f;
        for (int e = 0; e < cnt; ++e) {
            int ent = entries_t[e * NBUCKETS + j]; // coalesced across lanes
            int d = ent >> 1;
            unsigned sg = ((unsigned)ent & 1u) << 31;
            a0 += __uint_as_float(__float_as_uint(xs[0][d]) ^ sg);
            a1 += __uint_as_float(__float_as_uint(xs[1][d]) ^ sg);
            a2 += __uint_as_float(__float_as_uint(xs[2][d]) ^ sg);
            a3 += __uint_as_float(__float_as_uint(xs[3][d]) ^ sg);
        }
        size_t o = (size_t)n0 * NBUCKETS + j; // coalesced stores
        out[o]                = a0 * scale;
        out[o + NBUCKETS]     = a1 * scale;
        out[o + 2 * NBUCKETS] = a2 * scale;
        out[o + 3 * NBUCKETS] = a3 * scale;
    }
}

extern "C" void kernel_launch(void* const* d_in, const int* in_sizes, int n_in,
                              void* d_out, int out_size, void* d_ws, size_t ws_size,
                              hipStream_t stream)
{
    const float* x      = (const float*)d_in[0];
    const float* s_hash = (const float*)d_in[1];
    const int*   i_hash = (const int*)d_in[2];
    float* out = (float*)d_out;

    // ws layout: counts[4096] ints, then entries_t[CAP*4096] ints (~528 KiB)
    int* counts    = (int*)d_ws;
    int* entries_t = counts + NBUCKETS;

    cs_build_index<<<(NBUCKETS * 64) / 256, 256, 0, stream>>>(i_hash, s_hash, counts, entries_t);
    cs_gather<<<NROWS / ROWS_PER_WG, THREADS, 0, stream>>>(x, counts, entries_t, out);
}

// Round 3
// 79.319 us; speedup vs baseline: 4.0448x; 1.1910x over previous
//
#include <hip/hip_runtime.h>
#include <cstddef>

#define NUM_BLOCKS 8
#define BLK 512
#define D_IN 2048
#define NROWS 8192
#define NBUCKETS (NUM_BLOCKS * BLK) /* 4096 */
#define CAP 32                      /* padded capacity per bucket, mult of 4 */
#define ROWS_PER_WG 4
#define THREADS 512
#define XS_STRIDE 2052              /* 2048 + 4 zero pad; sentinel d = 2048 */
#define SENT_ENT (D_IN << 1)        /* sentinel entry: d=2048, sign + */

// Build inverted index: one WAVE per bucket. Lanes scan 64 dims per step,
// ballot-match, place matches in ascending-d order via popcount prefix into
// row-major entries[bucket][CAP]. Pad to a multiple of 4 with sentinels
// (d=2048 -> zeroed LDS slot in the gather kernel). nchunks = #int4 chunks.
__global__ __launch_bounds__(256) void cs_build_index(
    const int* __restrict__ i_hash, const float* __restrict__ s_hash,
    int* __restrict__ nchunks, int* __restrict__ entries)
{
    const int gid  = blockIdx.x * blockDim.x + threadIdx.x;
    const int wave = gid >> 6;            // bucket id in [0, 4096)
    const int lane = threadIdx.x & 63;
    if (wave >= NBUCKETS) return;
    const int b = wave >> 9;
    const int k = wave & (BLK - 1);
    const int*   ih = i_hash + b * D_IN;
    const float* sr = s_hash + b * D_IN;
    int* erow = entries + wave * CAP;
    int cnt = 0;
    for (int d0 = 0; d0 < D_IN; d0 += 64) {
        const int d = d0 + lane;
        const bool m = (ih[d] == k);      // coalesced load
        const unsigned long long mask = __ballot(m);
        if (m) {
            const int pos = cnt + __popcll(mask & ((1ull << lane) - 1ull));
            if (pos < CAP) {
                const int sg = (sr[d] < 0.0f) ? 1 : 0;
                erow[pos] = (d << 1) | sg;
            }
        }
        cnt += (int)__popcll(mask);
    }
    if (cnt > CAP) cnt = CAP;
    int nch = (cnt + 3) >> 2;
    if (nch == 0) nch = 1;                // empty bucket -> 1 all-sentinel chunk
    // pad [cnt, nch*4) with sentinels (nch*4 <= 32 < 64, one predicated store)
    if (lane >= cnt && lane < nch * 4) erow[lane] = SENT_ENT;
    if (lane == 0) nchunks[wave] = nch;
}

// Gather: each 512-thread WG stages 4 rows of x in LDS (with a zeroed
// 4-float sentinel pad per row), then each thread produces 8 buckets x 4
// rows. Entry loads are int4 (4 entries/load) from the L2-resident ELL
// table; output stores are coalesced.
__global__ __launch_bounds__(THREADS) void cs_gather(
    const float* __restrict__ x, const int* __restrict__ nchunks,
    const int* __restrict__ entries, float* __restrict__ out)
{
    __shared__ float xs[ROWS_PER_WG][XS_STRIDE]; // ~33 KiB
    const int tid = threadIdx.x;
    const int n0  = blockIdx.x * ROWS_PER_WG;

    // Stage 4 rows: 2048 float4 total, 4 per thread, coalesced.
    const float4* __restrict__ xv = (const float4*)(x + (size_t)n0 * D_IN);
#pragma unroll
    for (int i = 0; i < (ROWS_PER_WG * D_IN / 4) / THREADS; ++i) {
        const int idx = i * THREADS + tid;        // 0..2047
        const int r   = idx >> 9;                 // row
        const int c   = idx & 511;                // float4 within row
        ((float4*)&xs[r][0])[c] = xv[(size_t)r * 512 + c];
    }
    // zero the sentinel pad (d = 2048..2051) of each row
    if (tid < ROWS_PER_WG * 4) xs[tid >> 2][D_IN + (tid & 3)] = 0.0f;
    __syncthreads();

    const float scale = 0.35355339059327373f; // 1/sqrt(8)

#define PROC(ent)                                                        \
    do {                                                                 \
        const int d = (ent) >> 1;                                        \
        const unsigned sg = ((unsigned)(ent) & 1u) << 31;                \
        a0 += __uint_as_float(__float_as_uint(xs[0][d]) ^ sg);           \
        a1 += __uint_as_float(__float_as_uint(xs[1][d]) ^ sg);           \
        a2 += __uint_as_float(__float_as_uint(xs[2][d]) ^ sg);           \
        a3 += __uint_as_float(__float_as_uint(xs[3][d]) ^ sg);           \
    } while (0)

#pragma unroll 1
    for (int jj = 0; jj < NBUCKETS / THREADS; ++jj) {   // 8 buckets/thread
        const int j = jj * THREADS + tid;
        const int nch = nchunks[j];                     // coalesced
        const int4* __restrict__ ep = (const int4*)(entries + j * CAP);
        float a0 = 0.f, a1 = 0.f, a2 = 0.f, a3 = 0.f;
        int4 c0 = ep[0];                                // nch >= 1 always
        PROC(c0.x); PROC(c0.y); PROC(c0.z); PROC(c0.w);
#pragma unroll 1
        for (int c = 1; c < nch; ++c) {
            int4 cc = ep[c];
            PROC(cc.x); PROC(cc.y); PROC(cc.z); PROC(cc.w);
        }
        size_t o = (size_t)n0 * NBUCKETS + j;           // coalesced stores
        out[o]                = a0 * scale;
        out[o + NBUCKETS]     = a1 * scale;
        out[o + 2 * NBUCKETS] = a2 * scale;
        out[o + 3 * NBUCKETS] = a3 * scale;
    }
#undef PROC
}

extern "C" void kernel_launch(void* const* d_in, const int* in_sizes, int n_in,
                              void* d_out, int out_size, void* d_ws, size_t ws_size,
                              hipStream_t stream)
{
    const float* x      = (const float*)d_in[0];
    const float* s_hash = (const float*)d_in[1];
    const int*   i_hash = (const int*)d_in[2];
    float* out = (float*)d_out;

    // ws layout: nchunks[4096] ints, then entries[4096][CAP] ints (528 KiB)
    int* nchunks = (int*)d_ws;
    int* entries = nchunks + NBUCKETS;

    cs_build_index<<<(NBUCKETS * 64) / 256, 256, 0, stream>>>(i_hash, s_hash, nchunks, entries);
    cs_gather<<<NROWS / ROWS_PER_WG, THREADS, 0, stream>>>(x, nchunks, entries, out);
}